// Round 15
// baseline (6482.582 us; speedup 1.0000x reference)
//
#include <hip/hip_runtime.h>
#include <hip/hip_bf16.h>

#define B_SZ 1024
#define T_SZ 128
#define D_SZ 256
#define H_SZ 512
#define NBLK 256
#define NTHR 512
#define AUXS 0x1   // SC0 on state-panel loads: bypass L1, hit XCD-local L2

typedef __attribute__((ext_vector_type(8))) short short8;
typedef __attribute__((ext_vector_type(4))) float f32x4;

__device__ inline f32x4 mfma16(short8 a, short8 b, f32x4 c) {
  return __builtin_amdgcn_mfma_f32_16x16x32_bf16(a, b, c, 0, 0, 0);
}

// plain write-back state store (r13-proven visibility: vmcnt-drain + barrier)
__device__ inline void st_bf16(__hip_bfloat16* p, float v) {
  union { __hip_bfloat16 b; unsigned short u; } cv;
  cv.b = __float2bfloat16(v);
  unsigned int vv = cv.u;
  asm volatile("global_store_short %0, %1, off" :: "v"(p), "v"(vv) : "memory");
}

// Stage an NT-tile A-panel (each tile 32 rows x 64 cols bf16) into LDS,
// slot-swizzled (slot s of row r holds k-slot s^(r&7)); linear LDS dest +
// inverse-swizzled global source. One shot per phase; NT*256 % 512 == 0.
template <int NT, typename F>
__device__ __forceinline__ void stagePanel(unsigned short* pan, int tid, F src) {
#pragma unroll
  for (int it = 0; it * NTHR < NT * 256; ++it) {
    int c = it * NTHR + tid;           // chunk id (16B units)
    int tile = c >> 8, row = (c >> 3) & 31, slot = c & 7;
    int ksrc = (slot ^ (row & 7)) << 3;
    const __hip_bfloat16* g = src(tile, row, ksrc);
    unsigned short* l = pan + (size_t)(it * NTHR + ((tid >> 6) << 6)) * 8;
    __builtin_amdgcn_global_load_lds(
        (const __attribute__((address_space(1))) unsigned int*)g,
        (__attribute__((address_space(3))) unsigned int*)l, 16, 0, AUXS);
  }
}

__device__ __forceinline__ short8 ldfrag(const unsigned short* lds, int row, int slot) {
  int s = slot ^ (row & 7);
  return *(const short8*)(lds + row * 64 + s * 8);
}

// Strip-local 8-block barrier: monotonic counter, relaxed atomics, no fences.
__device__ __forceinline__ void sbar(unsigned* scnt, unsigned p) {
  asm volatile("s_waitcnt vmcnt(0)" ::: "memory");  // all waves drain stores
  __syncthreads();
  if (threadIdx.x == 0) {
    __hip_atomic_fetch_add(scnt, 1u, __ATOMIC_RELAXED, __HIP_MEMORY_SCOPE_AGENT);
    while (__hip_atomic_load(scnt, __ATOMIC_RELAXED, __HIP_MEMORY_SCOPE_AGENT) < p * 8u)
      __builtin_amdgcn_s_sleep(1);
  }
  __syncthreads();
}

__global__ __launch_bounds__(512, 2) void k_fused(
    const float* __restrict__ xg, const float* __restrict__ xtime,
    const __hip_bfloat16* __restrict__ W1t, const float* __restrict__ b1,
    const __hip_bfloat16* __restrict__ W2t, const float* __restrict__ b2,
    const __hip_bfloat16* __restrict__ Wzrt, const float* __restrict__ bz,
    const float* __restrict__ br, const __hip_bfloat16* __restrict__ Wnt,
    const float* __restrict__ bn, float* __restrict__ hf, float* __restrict__ hstdf,
    __hip_bfloat16* __restrict__ hbf, __hip_bfloat16* __restrict__ Ubf,
    __hip_bfloat16* __restrict__ hodeb, __hip_bfloat16* __restrict__ hstdb,
    __hip_bfloat16* __restrict__ A4, __hip_bfloat16* __restrict__ xstep,
    unsigned* __restrict__ bar) {
  // single A-panel: up to 20 tiles x (32x64) bf16 = 80 KB. B never touches
  // LDS (direct global->VGPR per wave) -> no per-k-tile cross-wave sync.
  __shared__ __align__(16) unsigned short pan[20 * 32 * 64];
  int tid = threadIdx.x, lane = tid & 63, wv = tid >> 6;
  int lr = lane & 15, lg = lane >> 4;
  int rh = wv >> 2, cq = wv & 3;   // wave role: row-half (0/1), col-quarter
  int b = blockIdx.x;
  // r13 mapping: strips co-located per XCD (4 strips x 8 slices per XCD)
  int xcd = b & 7;
  int j = b >> 3;
  int i = (xcd << 2) | (j >> 3);   // strip 0..31
  int s = j & 7;                   // slice 0..7
  int m0 = i << 5;                 // 32-row strip
  int nA = s << 6;                 // owned 64-column base (ALL phases)
  unsigned* scnt = bar + i * 32;
  unsigned p = 0;
  int cl = (cq << 4) + lr;
  int col = nA + cl;
  int row0 = m0 + (rh << 4) + (lg << 2);
  float hreg[4] = {0.f, 0.f, 0.f, 0.f}, sreg[4] = {0.f, 0.f, 0.f, 0.f};
  float oreg[4], zreg[4];

  // per-wave B pointers (lane-resolved): W^T row = output col, 16B frags
  const __hip_bfloat16* w1p = W1t + (size_t)(nA + cl) * H_SZ + (lg << 3);
  const __hip_bfloat16* w2p = W2t + (size_t)(nA + cl) * H_SZ + (lg << 3);
  const __hip_bfloat16* wzp = Wzrt + (size_t)(nA + cl) * 1280 + (lg << 3);
  const __hip_bfloat16* wrp = Wzrt + (size_t)(512 + nA + cl) * 1280 + (lg << 3);
  const __hip_bfloat16* wmp = Wnt + (size_t)(nA + cl) * 1280 + (lg << 3);
  const __hip_bfloat16* wsp = Wnt + (size_t)(512 + nA + cl) * 1280 + (lg << 3);

#pragma unroll 1
  for (int t = 0; t < T_SZ; ++t) {
    sbar(scnt, ++p);  // strip's hbf/hstdb of step t-1 visible
    // ======== P1: U = tanh(h @ W1 + b1), owned cols ========
    {
      stagePanel<8>(pan, tid, [&](int tile, int row, int ks) {
        return hbf + (size_t)(m0 + row) * H_SZ + (tile << 6) + ks;
      });
      asm volatile("s_waitcnt vmcnt(0)" ::: "memory");
      __syncthreads();
      f32x4 acc = {};
#pragma unroll
      for (int kt = 0; kt < 8; ++kt)
#pragma unroll
        for (int kk = 0; kk < 2; ++kk) {
          short8 a = ldfrag(pan + (kt << 11), (rh << 4) + lr, (kk << 2) + lg);
          short8 bb = *(const short8*)(w1p + (kt << 6) + (kk << 5));
          acc = mfma16(a, bb, acc);
        }
      float bi = b1[col];
#pragma unroll
      for (int r = 0; r < 4; ++r)
        st_bf16(&Ubf[(size_t)(row0 + r) * H_SZ + col], tanhf(acc[r] + bi));
    }
    sbar(scnt, ++p);
    // ======== P2: h_ode = h + dt*(U @ W2 + b2); x slice -> bf16 ========
    {
      stagePanel<8>(pan, tid, [&](int tile, int row, int ks) {
        return Ubf + (size_t)(m0 + row) * H_SZ + (tile << 6) + ks;
      });
      asm volatile("s_waitcnt vmcnt(0)" ::: "memory");
      __syncthreads();
      f32x4 acc = {};
#pragma unroll
      for (int kt = 0; kt < 8; ++kt)
#pragma unroll
        for (int kk = 0; kk < 2; ++kk) {
          short8 a = ldfrag(pan + (kt << 11), (rh << 4) + lr, (kk << 2) + lg);
          short8 bb = *(const short8*)(w2p + (kt << 6) + (kk << 5));
          acc = mfma16(a, bb, acc);
        }
      float dtv = (t == 0) ? 0.01f : (xtime[t] - xtime[t - 1]);
      float bi = b2[col];
#pragma unroll
      for (int r = 0; r < 4; ++r) {
        float v = hreg[r] + dtv * (acc[r] + bi);
        oreg[r] = v;
        st_bf16(&hodeb[(size_t)(row0 + r) * H_SZ + col], v);
      }
      {  // x[:, t, s-slice] -> bf16 (32 strip rows, 32 cols per slice)
        int colx = (s << 5) + (tid & 31);
#pragma unroll
        for (int it2 = 0; it2 < 2; ++it2) {
          int row = m0 + (tid >> 5) + (it2 << 4);
          float xv = xg[((size_t)row * T_SZ + t) * D_SZ + colx];
          st_bf16(&xstep[(size_t)row * D_SZ + colx], xv);
        }
      }
    }
    sbar(scnt, ++p);
    // ======== P3: z,r = sigmoid(cat @ WzrT), owned cols; build A4 ========
    {
      stagePanel<20>(pan, tid, [&](int tile, int row, int ks) -> const __hip_bfloat16* {
        int ke = tile << 6;
        if (ke < 512)  return hodeb + (size_t)(m0 + row) * H_SZ + ke + ks;
        if (ke < 1024) return hstdb + (size_t)(m0 + row) * H_SZ + (ke - 512) + ks;
        return xstep + (size_t)(m0 + row) * D_SZ + (ke - 1024) + ks;
      });
      asm volatile("s_waitcnt vmcnt(0)" ::: "memory");
      __syncthreads();
      f32x4 acc0 = {}, acc1 = {};
#pragma unroll
      for (int kt = 0; kt < 20; ++kt)
#pragma unroll
        for (int kk = 0; kk < 2; ++kk) {
          short8 a = ldfrag(pan + (kt << 11), (rh << 4) + lr, (kk << 2) + lg);
          short8 b0 = *(const short8*)(wzp + (kt << 6) + (kk << 5));
          short8 b1f = *(const short8*)(wrp + (kt << 6) + (kk << 5));
          acc0 = mfma16(a, b0, acc0);
          acc1 = mfma16(a, b1f, acc1);
        }
      float bz_ = bz[col], br_ = br[col];
#pragma unroll
      for (int r = 0; r < 4; ++r) {
        int row = row0 + r;
        zreg[r] = 1.f / (1.f + expf(-(acc0[r] + bz_)));
        float g = 1.f / (1.f + expf(-(acc1[r] + br_)));
        st_bf16(&A4[(size_t)row * 1024 + col], oreg[r] * g);
        st_bf16(&A4[(size_t)row * 1024 + 512 + col], sreg[r] * g);
      }
    }
    sbar(scnt, ++p);
    // ======== P4: n_mean,n_std owned cols; GRU update in registers ========
    {
      stagePanel<20>(pan, tid, [&](int tile, int row, int ks) -> const __hip_bfloat16* {
        int ke = tile << 6;
        if (ke < 1024) return A4 + (size_t)(m0 + row) * 1024 + ke + ks;
        return xstep + (size_t)(m0 + row) * D_SZ + (ke - 1024) + ks;
      });
      asm volatile("s_waitcnt vmcnt(0)" ::: "memory");
      __syncthreads();
      f32x4 acc0 = {}, acc1 = {};
#pragma unroll
      for (int kt = 0; kt < 20; ++kt)
#pragma unroll
        for (int kk = 0; kk < 2; ++kk) {
          short8 a = ldfrag(pan + (kt << 11), (rh << 4) + lr, (kk << 2) + lg);
          short8 b0 = *(const short8*)(wmp + (kt << 6) + (kk << 5));
          short8 b1f = *(const short8*)(wsp + (kt << 6) + (kk << 5));
          acc0 = mfma16(a, b0, acc0);
          acc1 = mfma16(a, b1f, acc1);
        }
      float bm = bn[col], bs = bn[512 + col];
#pragma unroll
      for (int r = 0; r < 4; ++r) {
        int row = row0 + r;
        float z = zreg[r];
        float hn = (1.f - z) * (acc0[r] + bm) + z * oreg[r];
        hreg[r] = hn;
        st_bf16(&hbf[(size_t)row * H_SZ + col], hn);
        float ns = fabsf(acc1[r] + bs);
        float sn = fabsf((1.f - z) * ns + z * sreg[r]);
        sreg[r] = sn;
        st_bf16(&hstdb[(size_t)row * H_SZ + col], sn);
      }
    }
  }
  // final output: register state -> global
#pragma unroll
  for (int r = 0; r < 4; ++r) {
    int row = row0 + r;
    hf[(size_t)row * H_SZ + col] = hreg[r];
    hstdf[(size_t)row * H_SZ + col] = sreg[r];
  }
}

// =============== prep: W[k][n] f32  ->  Wt[n][k] bf16 =====================
__global__ void k_wt(const float* __restrict__ W, __hip_bfloat16* __restrict__ Wt,
                     int K, int N, int ld) {
  size_t i = (size_t)blockIdx.x * 256 + threadIdx.x;
  if (i >= (size_t)K * N) return;
  int n = (int)(i / K), k = (int)(i % K);
  Wt[(size_t)n * ld + k] = __float2bfloat16(W[(size_t)k * N + n]);
}

extern "C" void kernel_launch(void* const* d_in, const int* in_sizes, int n_in,
                              void* d_out, int out_size, void* d_ws, size_t ws_size,
                              hipStream_t stream) {
  const float* x     = (const float*)d_in[0];
  const float* xtime = (const float*)d_in[1];
  const float* W1    = (const float*)d_in[2];
  const float* b1    = (const float*)d_in[3];
  const float* W2    = (const float*)d_in[4];
  const float* b2    = (const float*)d_in[5];
  const float* Wz    = (const float*)d_in[6];
  const float* bz    = (const float*)d_in[7];
  const float* Wr    = (const float*)d_in[8];
  const float* br    = (const float*)d_in[9];
  const float* Wn    = (const float*)d_in[10];
  const float* bn    = (const float*)d_in[11];

  char* p = (char*)d_ws;
  __hip_bfloat16* W1t   = (__hip_bfloat16*)(p + 0);
  __hip_bfloat16* W2t   = (__hip_bfloat16*)(p + 524288);
  __hip_bfloat16* Wzrt  = (__hip_bfloat16*)(p + 1048576);
  __hip_bfloat16* Wnt   = (__hip_bfloat16*)(p + 3670016);
  float*          hf    = (float*)(p + 6291456);
  float*          hstdf = (float*)(p + 8388608);
  __hip_bfloat16* hbf   = (__hip_bfloat16*)(p + 14680064);
  __hip_bfloat16* Ubf   = (__hip_bfloat16*)(p + 15728640);
  __hip_bfloat16* hodeb = (__hip_bfloat16*)(p + 16777216);
  __hip_bfloat16* hstdb = (__hip_bfloat16*)(p + 17825792);
  __hip_bfloat16* A4    = (__hip_bfloat16*)(p + 18874368);
  __hip_bfloat16* xstep = (__hip_bfloat16*)(p + 20971520);
  unsigned*       bar   = (unsigned*)(p + 21495808);

  hipMemsetAsync(hbf, 0, 1048576, stream);
  hipMemsetAsync(hstdb, 0, 1048576, stream);
  hipMemsetAsync(bar, 0, 8192, stream);

  k_wt<<<(512 * 512 + 255) / 256, 256, 0, stream>>>(W1, W1t, 512, 512, 512);
  k_wt<<<(512 * 512 + 255) / 256, 256, 0, stream>>>(W2, W2t, 512, 512, 512);
  k_wt<<<(1280 * 512 + 255) / 256, 256, 0, stream>>>(Wz, Wzrt, 1280, 512, 1280);
  k_wt<<<(1280 * 512 + 255) / 256, 256, 0, stream>>>(Wr, Wzrt + (size_t)512 * 1280, 1280, 512, 1280);
  k_wt<<<(1280 * 1024 + 255) / 256, 256, 0, stream>>>(Wn, Wnt, 1280, 1024, 1280);

  // persistent kernel: r13 mapping; A-panel staged once per phase into LDS;
  // B-operands direct global->VGPR per wave; free-running k-loops (no
  // per-k-tile barriers/vmcnt); 4 strip barriers per step
  k_fused<<<NBLK, NTHR, 0, stream>>>(x, xtime, W1t, b1, W2t, b2, Wzrt, bz, br,
                                     Wnt, bn, hf, hstdf, hbf, Ubf,
                                     hodeb, hstdb, A4, xstep, bar);

  hipMemcpyAsync(d_out, hf, 2097152, hipMemcpyDeviceToDevice, stream);
  hipMemcpyAsync((char*)d_out + 2097152, hstdf, 2097152, hipMemcpyDeviceToDevice, stream);
}